// Round 1
// baseline (56.035 us; speedup 1.0000x reference)
//
#include <hip/hip_runtime.h>
#include <hip/hip_bf16.h>

// Problem constants (from reference)
#define N_NODES 100000
#define K_DIM   8
#define S_SAMP  2048
#define E_EDGE  131072

#define CS_BLOCKS 256   // blocks in colsum kernel
#define M2_BLOCKS 8     // blocks in M2 kernel (2048 samples / 256)

// Workspace layout (float offsets)
#define CS_PART_OFF   0            // CS_BLOCKS*8      = 2048
#define M2P_OFF       2048         // M2_BLOCKS*64     = 512
#define SPA_OFF       2560         // 1  (softplus(a))
#define PAIR_PART_OFF 2624         // S_SAMP/2         = 1024
#define SP_PART_OFF   3648         // E_EDGE/256       = 512
#define BS_OFF        4160         // S_SAMP           = 2048  (beta[sample_idx])
#define MS_OFF        6208         // S_SAMP*8         = 16384 (M rows)
#define ZT_OFF        22592        // N*8 = 800000     (softmax(Zp) transposed: zt[n][k])
#define VT_OFF        822592       // N*8 = 800000     (v[n] = M2 @ zt[n])
// total ~1.62M floats = 6.5 MB

// ---------------------------------------------------------------------------
// K1: per-column softmax of Zp, store zt[n][k]; accumulate per-block partial
//     colsum[k] = sum_n zt[n][k] * sigmoid(Gp[n][k])
// ---------------------------------------------------------------------------
__global__ __launch_bounds__(256) void k_colsum(const float* __restrict__ Zp,
                                                const float* __restrict__ Gp,
                                                float* __restrict__ W) {
    int tid = threadIdx.x;
    float part[8] = {0,0,0,0,0,0,0,0};
    for (int n = blockIdx.x * 256 + tid; n < N_NODES; n += CS_BLOCKS * 256) {
        float zv[8];
        float mx = -1e30f;
        #pragma unroll
        for (int k = 0; k < 8; ++k) {
            zv[k] = Zp[(size_t)k * N_NODES + n];
            mx = fmaxf(mx, zv[k]);
        }
        float den = 0.0f;
        #pragma unroll
        for (int k = 0; k < 8; ++k) { zv[k] = __expf(zv[k] - mx); den += zv[k]; }
        float inv = 1.0f / den;
        float4 g0 = *(const float4*)&Gp[(size_t)n * 8];
        float4 g1 = *(const float4*)&Gp[(size_t)n * 8 + 4];
        float g[8] = {g0.x, g0.y, g0.z, g0.w, g1.x, g1.y, g1.z, g1.w};
        float zt[8];
        #pragma unroll
        for (int k = 0; k < 8; ++k) {
            float z = zv[k] * inv;
            zt[k] = z;
            part[k] += z / (1.0f + __expf(-g[k]));
        }
        float4 o0 = {zt[0], zt[1], zt[2], zt[3]};
        float4 o1 = {zt[4], zt[5], zt[6], zt[7]};
        *(float4*)&W[ZT_OFF + (size_t)n * 8]     = o0;
        *(float4*)&W[ZT_OFF + (size_t)n * 8 + 4] = o1;
    }
    __shared__ float sred[4][8];
    int lane = tid & 63, wave = tid >> 6;
    #pragma unroll
    for (int k = 0; k < 8; ++k) {
        float x = part[k];
        #pragma unroll
        for (int off = 32; off; off >>= 1) x += __shfl_down(x, off, 64);
        if (lane == 0) sred[wave][k] = x;
    }
    __syncthreads();
    if (tid < 8)
        W[CS_PART_OFF + blockIdx.x * 8 + tid] =
            sred[0][tid] + sred[1][tid] + sred[2][tid] + sred[3][tid];
}

// ---------------------------------------------------------------------------
// K2: reduce colsum partials; compute sp_a; per-block partial of
//     M2[k][j] = sum_s zt[idx_s][k] * (zt[idx_s][j]*sigmoid(Gp[idx_s][j])/colsum[j])
// ---------------------------------------------------------------------------
__global__ __launch_bounds__(256) void k_m2(const float* __restrict__ a,
                                            const float* __restrict__ Gp,
                                            const int* __restrict__ sidx,
                                            float* __restrict__ W) {
    __shared__ float sinv[8];
    __shared__ float sred[4][64];
    int tid = threadIdx.x;
    if (tid < 8) {
        float s = 0.0f;
        for (int b = 0; b < CS_BLOCKS; ++b) s += W[CS_PART_OFF + b * 8 + tid];
        sinv[tid] = 1.0f / s;
    }
    if (blockIdx.x == 0 && tid == 0) {
        float av = a[0];
        W[SPA_OFF] = fmaxf(av, 0.0f) + log1pf(__expf(-fabsf(av)));  // softplus
    }
    __syncthreads();

    int s = blockIdx.x * 256 + tid;            // exactly S_SAMP threads total
    int idx = sidx[s];
    float4 z0 = *(const float4*)&W[ZT_OFF + (size_t)idx * 8];
    float4 z1 = *(const float4*)&W[ZT_OFF + (size_t)idx * 8 + 4];
    float4 g0 = *(const float4*)&Gp[(size_t)idx * 8];
    float4 g1 = *(const float4*)&Gp[(size_t)idx * 8 + 4];
    float z[8] = {z0.x, z0.y, z0.z, z0.w, z1.x, z1.y, z1.z, z1.w};
    float g[8] = {g0.x, g0.y, g0.z, g0.w, g1.x, g1.y, g1.z, g1.w};
    float cs[8];
    #pragma unroll
    for (int j = 0; j < 8; ++j)
        cs[j] = z[j] * sinv[j] / (1.0f + __expf(-g[j]));

    int lane = tid & 63, wave = tid >> 6;
    #pragma unroll
    for (int k = 0; k < 8; ++k) {
        #pragma unroll
        for (int j = 0; j < 8; ++j) {
            float x = z[k] * cs[j];
            #pragma unroll
            for (int off = 32; off; off >>= 1) x += __shfl_down(x, off, 64);
            if (lane == 0) sred[wave][k * 8 + j] = x;
        }
    }
    __syncthreads();
    if (tid < 64)
        W[M2P_OFF + blockIdx.x * 64 + tid] =
            sred[0][tid] + sred[1][tid] + sred[2][tid] + sred[3][tid];
}

// ---------------------------------------------------------------------------
// K3: reduce M2 partials into LDS; v[n][k] = sum_j M2[k][j] * zt[n][j]
// ---------------------------------------------------------------------------
__global__ __launch_bounds__(256) void k_v(float* __restrict__ W) {
    __shared__ float sM2[64];
    int tid = threadIdx.x;
    if (tid < 64) {
        float m = 0.0f;
        #pragma unroll
        for (int b = 0; b < M2_BLOCKS; ++b) m += W[M2P_OFF + b * 64 + tid];
        sM2[tid] = m;
    }
    __syncthreads();
    int n = blockIdx.x * 256 + tid;
    if (n >= N_NODES) return;
    float4 z0 = *(const float4*)&W[ZT_OFF + (size_t)n * 8];
    float4 z1 = *(const float4*)&W[ZT_OFF + (size_t)n * 8 + 4];
    float z[8] = {z0.x, z0.y, z0.z, z0.w, z1.x, z1.y, z1.z, z1.w};
    float v[8];
    #pragma unroll
    for (int k = 0; k < 8; ++k) {
        float acc = 0.0f;
        #pragma unroll
        for (int j = 0; j < 8; ++j) acc += sM2[k * 8 + j] * z[j];
        v[k] = acc;
    }
    float4 o0 = {v[0], v[1], v[2], v[3]};
    float4 o1 = {v[4], v[5], v[6], v[7]};
    *(float4*)&W[VT_OFF + (size_t)n * 8]     = o0;
    *(float4*)&W[VT_OFF + (size_t)n * 8 + 4] = o1;
}

// ---------------------------------------------------------------------------
// K4: gather sampled rows: Ms[s][:] = v[idx_s][:], Bs[s] = beta[idx_s]
// ---------------------------------------------------------------------------
__global__ __launch_bounds__(256) void k_ms(const float* __restrict__ beta,
                                            const int* __restrict__ sidx,
                                            float* __restrict__ W) {
    int s = blockIdx.x * 256 + threadIdx.x;
    if (s >= S_SAMP) return;
    int idx = sidx[s];
    float4 v0 = *(const float4*)&W[VT_OFF + (size_t)idx * 8];
    float4 v1 = *(const float4*)&W[VT_OFF + (size_t)idx * 8 + 4];
    *(float4*)&W[MS_OFF + (size_t)s * 8]     = v0;
    *(float4*)&W[MS_OFF + (size_t)s * 8 + 4] = v1;
    W[BS_OFF + s] = beta[idx];
}

// ---------------------------------------------------------------------------
// K5: pairwise sum over s != t of exp(b_s + b_t - sp_a * ||M[s]-M[t]+1e-6||)
//     block b handles rows {2b, 2b+1}; per-block partial to W.
// ---------------------------------------------------------------------------
__global__ __launch_bounds__(256) void k_pair(float* __restrict__ W) {
    int tid = threadIdx.x;
    float sp_a = W[SPA_OFF];
    const float* Ms = W + MS_OFF;
    const float* Bs = W + BS_OFF;
    float acc = 0.0f;
    #pragma unroll
    for (int r = 0; r < 2; ++r) {
        int s = blockIdx.x * 2 + r;
        float4 m0 = *(const float4*)&Ms[(size_t)s * 8];
        float4 m1 = *(const float4*)&Ms[(size_t)s * 8 + 4];
        float bsv = Bs[s];
        for (int t = tid; t < S_SAMP; t += 256) {
            float4 a0 = *(const float4*)&Ms[(size_t)t * 8];
            float4 a1 = *(const float4*)&Ms[(size_t)t * 8 + 4];
            float d, ss;
            d = m0.x - a0.x + 1e-6f; ss  = d * d;
            d = m0.y - a0.y + 1e-6f; ss += d * d;
            d = m0.z - a0.z + 1e-6f; ss += d * d;
            d = m0.w - a0.w + 1e-6f; ss += d * d;
            d = m1.x - a1.x + 1e-6f; ss += d * d;
            d = m1.y - a1.y + 1e-6f; ss += d * d;
            d = m1.z - a1.z + 1e-6f; ss += d * d;
            d = m1.w - a1.w + 1e-6f; ss += d * d;
            float val = __expf(bsv + Bs[t] - sp_a * sqrtf(ss));
            if (t != s) acc += val;
        }
    }
    __shared__ float sw[4];
    int lane = tid & 63, wave = tid >> 6;
    #pragma unroll
    for (int off = 32; off; off >>= 1) acc += __shfl_down(acc, off, 64);
    if (lane == 0) sw[wave] = acc;
    __syncthreads();
    if (tid == 0) W[PAIR_PART_OFF + blockIdx.x] = sw[0] + sw[1] + sw[2] + sw[3];
}

// ---------------------------------------------------------------------------
// K6: sparse edges: sum_e beta_i + beta_j - sp_a * ||v[i]-v[j]+1e-6||
// ---------------------------------------------------------------------------
__global__ __launch_bounds__(256) void k_sparse(const float* __restrict__ beta,
                                                const int* __restrict__ si,
                                                const int* __restrict__ sj,
                                                float* __restrict__ W) {
    int tid = threadIdx.x;
    int e = blockIdx.x * 256 + tid;   // grid covers E exactly
    float sp_a = W[SPA_OFF];
    int i = si[e], j = sj[e];
    const float* vt = W + VT_OFF;
    float4 vi0 = *(const float4*)&vt[(size_t)i * 8];
    float4 vi1 = *(const float4*)&vt[(size_t)i * 8 + 4];
    float4 vj0 = *(const float4*)&vt[(size_t)j * 8];
    float4 vj1 = *(const float4*)&vt[(size_t)j * 8 + 4];
    float d, ss;
    d = vi0.x - vj0.x + 1e-6f; ss  = d * d;
    d = vi0.y - vj0.y + 1e-6f; ss += d * d;
    d = vi0.z - vj0.z + 1e-6f; ss += d * d;
    d = vi0.w - vj0.w + 1e-6f; ss += d * d;
    d = vi1.x - vj1.x + 1e-6f; ss += d * d;
    d = vi1.y - vj1.y + 1e-6f; ss += d * d;
    d = vi1.z - vj1.z + 1e-6f; ss += d * d;
    d = vi1.w - vj1.w + 1e-6f; ss += d * d;
    float acc = beta[i] + beta[j] - sp_a * sqrtf(ss);

    __shared__ float sw[4];
    int lane = tid & 63, wave = tid >> 6;
    #pragma unroll
    for (int off = 32; off; off >>= 1) acc += __shfl_down(acc, off, 64);
    if (lane == 0) sw[wave] = acc;
    __syncthreads();
    if (tid == 0) W[SP_PART_OFF + blockIdx.x] = sw[0] + sw[1] + sw[2] + sw[3];
}

// ---------------------------------------------------------------------------
// K7: final combine: out = z_pdist2 - 0.5*e^2 * pair_sum
// ---------------------------------------------------------------------------
__global__ __launch_bounds__(256) void k_final(const float* __restrict__ W,
                                               float* __restrict__ out) {
    __shared__ double sd[256];
    int tid = threadIdx.x;
    double ap = 0.0, as = 0.0;
    for (int i = tid; i < S_SAMP / 2; i += 256) ap += (double)W[PAIR_PART_OFF + i];
    for (int i = tid; i < E_EDGE / 256; i += 256) as += (double)W[SP_PART_OFF + i];
    sd[tid] = as - 0.5 * 7.3890560989306495 * ap;  // e^2
    __syncthreads();
    for (int s = 128; s > 0; s >>= 1) {
        if (tid < s) sd[tid] += sd[tid + s];
        __syncthreads();
    }
    if (tid == 0) out[0] = (float)sd[0];
}

extern "C" void kernel_launch(void* const* d_in, const int* in_sizes, int n_in,
                              void* d_out, int out_size, void* d_ws, size_t ws_size,
                              hipStream_t stream) {
    const float* beta       = (const float*)d_in[0];
    const float* a          = (const float*)d_in[1];
    const float* Zp         = (const float*)d_in[2];
    const float* Gp         = (const float*)d_in[3];
    const int*   sample_idx = (const int*)d_in[4];
    const int*   sparse_i   = (const int*)d_in[5];
    const int*   sparse_j   = (const int*)d_in[6];
    float* out = (float*)d_out;
    float* W   = (float*)d_ws;

    k_colsum<<<dim3(CS_BLOCKS), dim3(256), 0, stream>>>(Zp, Gp, W);
    k_m2<<<dim3(M2_BLOCKS), dim3(256), 0, stream>>>(a, Gp, sample_idx, W);
    k_v<<<dim3((N_NODES + 255) / 256), dim3(256), 0, stream>>>(W);
    k_ms<<<dim3(S_SAMP / 256), dim3(256), 0, stream>>>(beta, sample_idx, W);
    k_pair<<<dim3(S_SAMP / 2), dim3(256), 0, stream>>>(W);
    k_sparse<<<dim3(E_EDGE / 256), dim3(256), 0, stream>>>(beta, sparse_i, sparse_j, W);
    k_final<<<dim3(1), dim3(256), 0, stream>>>(W, out);
}